// Round 3
// baseline (252.742 us; speedup 1.0000x reference)
//
#include <hip/hip_runtime.h>

#define NB     64
#define CCH    256
#define HW     20480       // 128*160
#define PXB    1024        // px per block
#define NPR    (HW/PXB)    // 20 pixel ranges
#define GRID_MS (2*4*16*NPR)   // 2560 blocks

// Workspace layout (bytes):
//   sums [2 replicas][2 tensors][64][256] f32 = 262144, zeroed
//   counts [65] i32 @ 262144 ; acc @ 262404 ; ticket @ 262408 ; memset [0,262412)
#define REP_STRIDE (2 * NB * CCH)
#define WS_COUNTS 262144
#define WS_ACC    262404
#define WS_TICKET 262408
#define WS_ZERO   262412

typedef __attribute__((ext_vector_type(8))) short short8;
typedef __attribute__((ext_vector_type(4))) float f32x4;

// ---------------------------------------------------------------------------
// Main: segment-sum as one-hot MFMA.
// R8: NO feature LDS. The verified B-frag layout (n=lane&15, k=q*8+j) is
// directly loadable: lane L loads channel (L&15), px (L>>4)*8 .. +8 as two
// float4s, converts to bf16 in-register, feeds MFMA. Removes the ds_write/
// ds_read/barrier convoy that R0/R6/R7 all shared (all ~66us regardless of
// memory residency -> structure-bound, not BW-bound). LDS drops to 17.7 KB
// (sBin + hist + reduce) -> 6 blocks/CU. 2 barriers total (was 4).
// Layouts (R3-R5 verified): A: m=lane&15,k=q*8+j; B: n=lane&15,k=q*8+j;
// D: col=lane&15,row=q*4+reg.
__global__ __launch_bounds__(256, 6)
void k_msum(const float* __restrict__ predsS,
            const float* __restrict__ predsT,
            const float* __restrict__ depth,
            float* __restrict__ sums,
            int* __restrict__ counts) {
    int tid = threadIdx.x;
    int blk = blockIdx.x;
    int prange = blk % NPR;
    int group  = blk / NPR;          // 0..127 = [tensor:1][n:2][cg:4]
    int tensor = group >> 6;
    int n  = (group >> 4) & 3;
    int cg = group & 15;
    int px0 = prange * PXB;

    const float* xbase = (tensor ? predsT : predsS)
                       + (size_t)(n * CCH + cg * 16) * HW + px0;
    const float* dbase = depth + n * HW + px0;

    __shared__ unsigned char sBin[PXB];      // 1 KB
    __shared__ int lhist[NB + 1];
    __shared__ float red[4096];              // 16 KB cross-wave reduce

    int lane = tid & 63, wv = tid >> 6;
    int l15 = lane & 15, q = lane >> 4;

    // Depth loads first (independent, fly under feature loads).
    float dv[4];
    #pragma unroll
    for (int r = 0; r < 4; ++r) dv[r] = dbase[tid + r * 256];

    // This lane's fragment stream: channel l15, px base wv*256 + q*8.
    // Fragment ks lives at fb + ks*32 (two float4s: +0, +4).
    const float* fb = xbase + (size_t)l15 * HW + wv * 256 + q * 8;
    float4 va[4], vb[4];                     // 4-deep prefetch (32 VGPR)
    #pragma unroll
    for (int p = 0; p < 4; ++p) {
        va[p] = *(const float4*)(fb + p * 32);
        vb[p] = *(const float4*)(fb + p * 32 + 4);
    }

    bool desig = (tensor == 0) && (cg == 0); // 80 blocks cover depth exactly once
    if (desig && tid < NB + 1) lhist[tid] = 0;

    #pragma unroll
    for (int r = 0; r < 4; ++r) {            // binning (waits only on dv loads)
        float f = dv[r] * 64.0f;
        int b;
        if (!(f >= 0.0f) || f > 64.0f) b = NB;   // NaN via !(f>=0)
        else b = (int)f;                          // f==64.0 -> 64 (matches ref)
        sBin[tid + r * 256] = (unsigned char)b;
    }

    f32x4 acc[4];
    #pragma unroll
    for (int mt = 0; mt < 4; ++mt) acc[mt] = (f32x4)0.0f;

    __syncthreads();   // sBin ready (barrier 1 of 2)

    #pragma unroll
    for (int ks = 0; ks < 8; ++ks) {
        int pi = ks & 3;
        unsigned long long bv = *(const unsigned long long*)&sBin[wv * 256 + ks * 32 + q * 8];
        // convert current fragment to bf16 (round-half-up, R5-validated)
        float4 A = va[pi], B = vb[pi];
        unsigned u0 = __float_as_uint(A.x), u1 = __float_as_uint(A.y);
        unsigned u2 = __float_as_uint(A.z), u3 = __float_as_uint(A.w);
        unsigned u4 = __float_as_uint(B.x), u5 = __float_as_uint(B.y);
        unsigned u6 = __float_as_uint(B.z), u7 = __float_as_uint(B.w);
        union { short8 s; unsigned u[4]; } bh;
        bh.u[0] = ((u0 + 0x8000u) >> 16) | ((u1 + 0x8000u) & 0xFFFF0000u);
        bh.u[1] = ((u2 + 0x8000u) >> 16) | ((u3 + 0x8000u) & 0xFFFF0000u);
        bh.u[2] = ((u4 + 0x8000u) >> 16) | ((u5 + 0x8000u) & 0xFFFF0000u);
        bh.u[3] = ((u6 + 0x8000u) >> 16) | ((u7 + 0x8000u) & 0xFFFF0000u);
        if (ks < 4) {   // prefetch ks+4 (after convert freed the regs)
            va[pi] = *(const float4*)(fb + (ks + 4) * 32);
            vb[pi] = *(const float4*)(fb + (ks + 4) * 32 + 4);
        }
        #pragma unroll
        for (int mt = 0; mt < 4; ++mt) {
            int tgt = mt * 16 + l15;
            short8 afr;
            #pragma unroll
            for (int j = 0; j < 8; ++j)
                afr[j] = ((int)((bv >> (8 * j)) & 0xFFull) == tgt) ? (short)0x3F80 : (short)0;
            acc[mt] = __builtin_amdgcn_mfma_f32_16x16x32_bf16(afr, bh.s, acc[mt], 0, 0, 0);
        }
    }

    // cross-wave reduce (red unused until here -> no barrier needed pre-write)
    #pragma unroll
    for (int mt = 0; mt < 4; ++mt)
        #pragma unroll
        for (int r = 0; r < 4; ++r)
            red[wv * 1024 + (mt * 16 + q * 4 + r) * 16 + l15] = acc[mt][r];
    if (desig) {   // histogram overlaps reduce writes
        for (int i = tid; i < PXB; i += 256) atomicAdd(&lhist[sBin[i]], 1);
    }
    __syncthreads();   // barrier 2 of 2
    float* dst = sums + (size_t)(blk & 1) * REP_STRIDE
               + (size_t)tensor * NB * CCH + cg * 16;
    #pragma unroll
    for (int k = 0; k < 4; ++k) {
        int e = tid + k * 256;               // e = bin*16 + chLocal
        float s = red[e] + red[1024 + e] + red[2048 + e] + red[3072 + e];
        atomicAdd(&dst[(e >> 4) * CCH + (e & 15)], s);
    }
    if (desig && tid < NB + 1 && lhist[tid] != 0) atomicAdd(&counts[tid], lhist[tid]);
}

// ---------------------------------------------------------------------------
// Fused protos+sim: 64 blocks x 256 threads. Each block recomputes all 64
// per-bin norms itself from sums (256 KB L2-hot reads, ~2us) -- eliminates
// the separate k_protos dispatch. All op orders bit-identical to the old
// k_protos/k_sim pair: same butterfly tree, same division sequence, same
// float4 dot grouping.
__global__ __launch_bounds__(256) void k_psim(const float* __restrict__ sums,
                                              const int* __restrict__ counts,
                                              float* __restrict__ acc,
                                              unsigned int* __restrict__ ticket,
                                              float* __restrict__ out) {
    int i = blockIdx.x, t = threadIdx.x;
    int lane = t & 63, w = t >> 6;
    __shared__ float rowS[CCH], rowT[CCH];
    __shared__ float partS[NB][4], partT[NB][4];
    __shared__ float nS[NB], nT[NB];

    // Step 1: norms for all bins. Thread t holds channel k=t (wave w = ch
    // block w*64..w*64+63 -- same lane->channel partition as old k_protos).
    for (int s = 0; s < NB; ++s) {
        int ci = counts[s];
        float cnt = (float)(ci < 1 ? 1 : ci);
        float mS = (sums[s * CCH + t] + sums[REP_STRIDE + s * CCH + t]) / cnt;
        float mT = (sums[(NB + s) * CCH + t] + sums[REP_STRIDE + (NB + s) * CCH + t]) / cnt;
        if (s == i) { rowS[t] = mS; rowT[t] = mT; }
        float ss = mS * mS, st = mT * mT;
        #pragma unroll
        for (int o = 32; o; o >>= 1) {
            ss += __shfl_xor(ss, o, 64);
            st += __shfl_xor(st, o, 64);
        }
        if (lane == 0) { partS[s][w] = ss; partT[s][w] = st; }
    }
    __syncthreads();
    if (t < NB) {
        nS[t] = fmaxf(sqrtf(partS[t][0] + partS[t][1] + partS[t][2] + partS[t][3]), 1e-12f);
        nT[t] = fmaxf(sqrtf(partT[t][0] + partT[t][1] + partT[t][2] + partT[t][3]), 1e-12f);
    }
    __syncthreads();
    rowS[t] = rowS[t] / nS[i];   // row i normalized (same rounding as old pS)
    rowT[t] = rowT[t] / nT[i];
    __syncthreads();

    // Step 2: dots. Thread (j=lane, seg=w); proto row j recomputed on the fly.
    int j = lane, seg = w;
    int cj = counts[j];
    float cntj = (float)(cj < 1 ? 1 : cj);
    float nSj = nS[j], nTj = nT[j];
    const float4* aS = (const float4*)(sums + j * CCH + seg * 64);
    const float4* bS = (const float4*)(sums + REP_STRIDE + j * CCH + seg * 64);
    const float4* aT = (const float4*)(sums + (NB + j) * CCH + seg * 64);
    const float4* bT = (const float4*)(sums + REP_STRIDE + (NB + j) * CCH + seg * 64);
    const float4* Si = (const float4*)(rowS + seg * 64);
    const float4* Ti = (const float4*)(rowT + seg * 64);
    float dS = 0.0f, dT = 0.0f;
    #pragma unroll
    for (int k = 0; k < 16; ++k) {
        float4 x = aS[k], y = bS[k];
        float4 pj;
        pj.x = ((x.x + y.x) / cntj) / nSj;
        pj.y = ((x.y + y.y) / cntj) / nSj;
        pj.z = ((x.z + y.z) / cntj) / nSj;
        pj.w = ((x.w + y.w) / cntj) / nSj;
        float4 a = Si[k];
        dS += a.x * pj.x + a.y * pj.y + a.z * pj.z + a.w * pj.w;
        float4 u = aT[k], v = bT[k];
        float4 qj;
        qj.x = ((u.x + v.x) / cntj) / nTj;
        qj.y = ((u.y + v.y) / cntj) / nTj;
        qj.z = ((u.z + v.z) / cntj) / nTj;
        qj.w = ((u.w + v.w) / cntj) / nTj;
        float4 c = Ti[k];
        dT += c.x * qj.x + c.y * qj.y + c.z * qj.z + c.w * qj.w;
    }
    __shared__ float sS[4][64], sT[4][64];
    sS[seg][j] = dS;
    sT[seg][j] = dT;
    __syncthreads();
    if (t < 64) {
        float fS = sS[0][t] + sS[1][t] + sS[2][t] + sS[3][t];
        float fT = sT[0][t] + sT[1][t] + sT[2][t] + sT[3][t];
        float e = fS - fT;
        e = e * e;
        #pragma unroll
        for (int o = 32; o; o >>= 1) e += __shfl_xor(e, o, 64);
        if (t == 0) {
            atomicAdd(acc, e);
            __threadfence();
            unsigned int r = atomicAdd(ticket, 1u);
            if (r == NB - 1) {
                float tot = atomicAdd(acc, 0.0f);   // device-scope read
                out[0] = tot * (1.0f / (float)(NB * NB));
            }
        }
    }
}

extern "C" void kernel_launch(void* const* d_in, const int* in_sizes, int n_in,
                              void* d_out, int out_size, void* d_ws, size_t ws_size,
                              hipStream_t stream) {
    const float* predsS = (const float*)d_in[0];
    const float* predsT = (const float*)d_in[1];
    const float* depth  = (const float*)d_in[2];
    char* ws = (char*)d_ws;
    float* sums = (float*)ws;
    int* counts = (int*)(ws + WS_COUNTS);
    float* acc = (float*)(ws + WS_ACC);
    unsigned int* ticket = (unsigned int*)(ws + WS_TICKET);

    hipMemsetAsync(ws, 0, WS_ZERO, stream);
    k_msum<<<GRID_MS, 256, 0, stream>>>(predsS, predsT, depth, sums, counts);
    k_psim<<<NB, 256, 0, stream>>>(sums, counts, acc, ticket, (float*)d_out);
}